// Round 12
// baseline (173.121 us; speedup 1.0000x reference)
//
#include <hip/hip_runtime.h>
#include <math.h>
#include <stdint.h>

#define K_DIM 8192     // S*DIM
#define D_DIM 2048
#define M_ROWS 8192
#define N_W 32         // W columns (only 24 used in H)
#define NC 24
#define KSPLIT 8       // grid.y: 32 ksteps per block-column
#define ROWS 16        // rows per block = one MFMA tile
#define THR 256        // 4 waves; wave wv owns ksteps [ks0, ks0+8)
#define ITERS 8        // ksteps per wave

typedef short bf16x8 __attribute__((ext_vector_type(8)));
typedef float f32x4 __attribute__((ext_vector_type(4)));
union U32x4 { uint32_t u[4]; bf16x8 v; };

// wfrag (u16, W rne-bf16 hi-only): [ks(256)][tile(2)][lane(64)][e(8)] = 512 KB.
// Fragment (ks,tile) = contiguous 1KB; lane l reads 16B at l*16 -> coalesced.
#define WFI(ks, tile) (((ks) * 2 + (tile)) * 64)   // bf16x8 units

// ---------------------------------------------------------------------------
// Kernel 0: prepack W -> rne bf16 B-fragments (once); zero Hsum.
// k-map matches A-frag map: lane=((k&31)>>3)*16+(n&15), e=k&7 (same perm on
// both MFMA operands so it cancels; only C/D layout matters).
// ---------------------------------------------------------------------------
__global__ __launch_bounds__(256) void mhc_prepack_kernel(
    const float* __restrict__ W, unsigned short* __restrict__ wfrag,
    float* __restrict__ Hsum)
{
    const int idx = blockIdx.x * 256 + threadIdx.x;   // 0 .. 262143
    const int k = idx >> 5, n = idx & 31;
    const float w = W[(size_t)k * N_W + n];
    const uint32_t u = __float_as_uint(w);
    const uint32_t r = u + 0x7FFFu + ((u >> 16) & 1u);   // round-nearest-even

    const int ks = k >> 5, kk = k & 31;
    const int lane = ((kk >> 3) << 4) | (n & 15);
    const int e = kk & 7;
    const int tile = n >> 4;
    wfrag[((size_t)WFI(ks, tile) + lane) * 8 + e] = (unsigned short)(r >> 16);

    if (idx < M_ROWS * NC) Hsum[idx] = 0.f;
}

// ---------------------------------------------------------------------------
// Kernel 1: partial H via MFMA, H = Xhi@W + Xlo@W (X exact hi/lo split).
// BARRIER-FREE: each wave owns a private 2x2KB LDS double-buffer and runs an
// independent 8-iter pipeline over its 16-row x 32-k tiles:
//   global X  (8 lanes x 128B contiguous per row, 2 instrs = 2KB)
//   -> reg -> LDS (XOR swizzle: unit^(row&7); A-frag b128 reads 2-way = free)
//   -> 2x ds_read_b128 (A) + 2x 16B wfrag loads (B, L2, prefetched 1 ahead)
//   -> hi/lo pack -> 4 MFMA.
// Same-wave LDS ordering (lgkmcnt) makes this legal with no __syncthreads.
// 16KB LDS/block, ~20 waves/CU all streaming -> HBM never idles.
// fp32 atomicAdd combine. C/D: D[row=(l>>4)*4+reg][col=l&15]  [HW-verified].
// ---------------------------------------------------------------------------
__global__ __launch_bounds__(THR) void mhc_gemm_kernel(
    const float* __restrict__ X, const unsigned short* __restrict__ wfrag,
    float* __restrict__ Hsum)
{
    __shared__ __align__(16) float4 Xl[4][2][128];   // per-wave dbuf, 16 KB
    const int t = threadIdx.x;
    const int l = t & 63;
    const int wv = t >> 6;
    const int rowbase = blockIdx.x * ROWS;
    const int ks0 = blockIdx.y * 32 + wv * ITERS;

    const float4* __restrict__ Xg = reinterpret_cast<const float4*>(X);
    const bf16x8* __restrict__ wf = reinterpret_cast<const bf16x8*>(wfrag);

    const int lr = l >> 3;        // staging row sub (0..7)
    const int lu = l & 7;         // staging unit (16B) within 32-k row window
    const int arow = l & 15;      // A-frag row
    const int au = (l >> 4) * 2;  // A-frag first 16B unit

    f32x4 c0 = {0.f, 0.f, 0.f, 0.f};
    f32x4 c1 = {0.f, 0.f, 0.f, 0.f};
    float4 pa, pb;
    bf16x8 b0n, b1n;

    // ---- prologue: load + stage iter 0 ----
    pa = Xg[(size_t)(rowbase + lr) * (K_DIM / 4) + ks0 * 8 + lu];
    pb = Xg[(size_t)(rowbase + 8 + lr) * (K_DIM / 4) + ks0 * 8 + lu];
    b0n = wf[WFI(ks0, 0) + l];
    b1n = wf[WFI(ks0, 1) + l];
    Xl[wv][0][lr * 8 + (lu ^ lr)] = pa;
    Xl[wv][0][(8 + lr) * 8 + (lu ^ lr)] = pb;   // (8+lr)&7 == lr

#pragma unroll
    for (int i = 0; i < ITERS; ++i) {
        const bf16x8 b0 = b0n, b1 = b1n;
        if (i + 1 < ITERS) {   // prefetch next iter (X + B)
            const int ks = ks0 + i + 1;
            pa = Xg[(size_t)(rowbase + lr) * (K_DIM / 4) + ks * 8 + lu];
            pb = Xg[(size_t)(rowbase + 8 + lr) * (K_DIM / 4) + ks * 8 + lu];
            b0n = wf[WFI(ks, 0) + l];
            b1n = wf[WFI(ks, 1) + l];
        }

        // ---- A-frags from this wave's LDS (swizzled; 2-way = free) ----
        const float4 xa = Xl[wv][i & 1][arow * 8 + (au ^ (arow & 7))];
        const float4 xb = Xl[wv][i & 1][arow * 8 + ((au + 1) ^ (arow & 7))];
        float xs[8];
        xs[0] = xa.x; xs[1] = xa.y; xs[2] = xa.z; xs[3] = xa.w;
        xs[4] = xb.x; xs[5] = xb.y; xs[6] = xb.z; xs[7] = xb.w;

        U32x4 ah, al;
#pragma unroll
        for (int p = 0; p < 4; ++p) {
            const uint32_t u0 = __float_as_uint(xs[2 * p]);
            const uint32_t u1 = __float_as_uint(xs[2 * p + 1]);
            const float h0 = __uint_as_float(u0 & 0xFFFF0000u);
            const float h1 = __uint_as_float(u1 & 0xFFFF0000u);
            const uint32_t r0 = __float_as_uint(xs[2 * p] - h0);
            const uint32_t r1 = __float_as_uint(xs[2 * p + 1] - h1);
            ah.u[p] = (u1 & 0xFFFF0000u) | (u0 >> 16);
            al.u[p] = (r1 & 0xFFFF0000u) | (r0 >> 16);
        }

        c0 = __builtin_amdgcn_mfma_f32_16x16x32_bf16(ah.v, b0, c0, 0, 0, 0);
        c0 = __builtin_amdgcn_mfma_f32_16x16x32_bf16(al.v, b0, c0, 0, 0, 0);
        c1 = __builtin_amdgcn_mfma_f32_16x16x32_bf16(ah.v, b1, c1, 0, 0, 0);
        c1 = __builtin_amdgcn_mfma_f32_16x16x32_bf16(al.v, b1, c1, 0, 0, 0);

        if (i + 1 < ITERS) {   // stage next iter into the other buffer
            Xl[wv][(i + 1) & 1][lr * 8 + (lu ^ lr)] = pa;
            Xl[wv][(i + 1) & 1][(8 + lr) * 8 + (lu ^ lr)] = pb;
        }
    }

    // ---- combine: D[row=(l>>4)*4+r][col=l&15] ----
    const int drow = rowbase + ((l >> 4) << 2);
    const int col = l & 15;
#pragma unroll
    for (int r = 0; r < 4; ++r)
        atomicAdd(&Hsum[(size_t)(drow + r) * NC + col], c0[r]);
    if (col < 8) {
#pragma unroll
        for (int r = 0; r < 4; ++r)
            atomicAdd(&Hsum[(size_t)(drow + r) * NC + 16 + col], c1[r]);
    }
}

// ---------------------------------------------------------------------------
// Kernel 2: params (transform + sinkhorn) + apply. One block per row.
// ---------------------------------------------------------------------------
__global__ __launch_bounds__(256) void mhc_apply_kernel(
    const float* __restrict__ X, const float* __restrict__ Hsum,
    const float* __restrict__ ab, float* __restrict__ out)
{
    __shared__ float pbuf[NC];
    const int row = blockIdx.x;
    const int t = threadIdx.x;

    if (t < 64) {
        const int lane = t;
        const float pl = (lane < NC) ? Hsum[(size_t)row * NC + lane] : 0.f;
        const float bias  = (lane < NC) ? ab[lane] : 0.f;
        const float scale = ab[(lane < 16) ? 24 : ((lane < 20) ? 25 : 26)];

        float vout;
        if (lane < 16) {
            vout = __expf(fmaf(scale, pl, bias));                 // exp(a_res*H+b)
        } else {
            vout = fmaf(scale, 1.f / (1.f + __expf(-pl)), bias);  // a*sigmoid(H)+b
        }

        // Sinkhorn on lanes 0..15: lane = s*4 + i.
        float p = vout;
        for (int it = 0; it < 20; ++it) {
            float rs = p + __shfl_xor(p, 1);
            rs += __shfl_xor(rs, 2);
            p = p / rs;
            float cs = p + __shfl_xor(p, 4);
            cs += __shfl_xor(cs, 8);
            p = p / cs;
        }
        if (lane < NC) pbuf[lane] = (lane < 16) ? p : vout;
    }
    __syncthreads();

    float hres[4][4], hpre[4], hpos[4];
#pragma unroll
    for (int i = 0; i < 16; ++i) hres[i >> 2][i & 3] = pbuf[i];
#pragma unroll
    for (int i = 0; i < 4; ++i) hpre[i] = pbuf[16 + i];
#pragma unroll
    for (int i = 0; i < 4; ++i) hpos[i] = pbuf[20 + i];

    const float4* __restrict__ Xr =
        reinterpret_cast<const float4*>(X + (size_t)row * K_DIM);
    float4* __restrict__ Or = reinterpret_cast<float4*>(out + (size_t)row * K_DIM);

#pragma unroll
    for (int q = 0; q < 2; ++q) {
        const int pos = t + q * 256;          // float4 index within a 2048-seg
        float4 xq[4];
#pragma unroll
        for (int i = 0; i < 4; ++i) xq[i] = Xr[i * (D_DIM / 4) + pos];

        float y[4];
#pragma unroll
        for (int e = 0; e < 4; ++e) {
            float s = 0.f;
#pragma unroll
            for (int i = 0; i < 4; ++i)
                s = fmaf(hpre[i], reinterpret_cast<const float*>(&xq[i])[e], s);
            y[e] = s;
        }

#pragma unroll
        for (int s = 0; s < 4; ++s) {
            float4 o;
            float* oe = reinterpret_cast<float*>(&o);
#pragma unroll
            for (int e = 0; e < 4; ++e) {
                float v = hpos[s] * y[e];
#pragma unroll
                for (int i = 0; i < 4; ++i)
                    v = fmaf(hres[s][i], reinterpret_cast<const float*>(&xq[i])[e], v);
                oe[e] = v;
            }
            Or[s * (D_DIM / 4) + pos] = o;
        }
    }
}

extern "C" void kernel_launch(void* const* d_in, const int* in_sizes, int n_in,
                              void* d_out, int out_size, void* d_ws, size_t ws_size,
                              hipStream_t stream) {
    const float* X  = (const float*)d_in[0];
    const float* W  = (const float*)d_in[1];
    const float* ab = (const float*)d_in[2];
    float* out = (float*)d_out;
    unsigned short* wfrag = (unsigned short*)d_ws;          // 524,288 B
    float* Hsum = (float*)((char*)d_ws + 524288);           // + 786,432 B

    mhc_prepack_kernel<<<(K_DIM * N_W) / 256, 256, 0, stream>>>(W, wfrag, Hsum);
    dim3 g1(M_ROWS / ROWS, KSPLIT);
    mhc_gemm_kernel<<<g1, THR, 0, stream>>>(X, wfrag, Hsum);
    mhc_apply_kernel<<<M_ROWS, 256, 0, stream>>>(X, Hsum, ab, out);
}